// Round 16
// baseline (254.577 us; speedup 1.0000x reference)
//
#include <hip/hip_runtime.h>
#include <stdint.h>

#define N_GAUSS 1024
#define H_DIM 768
#define W_DIM 768
#define WL_STRIDE 1040  // fp16 W row stride: row bank offset 8 -> 2-way (free)

typedef _Float16 half8  __attribute__((ext_vector_type(8)));
typedef __fp16   fp16x2 __attribute__((ext_vector_type(2)));
typedef float    f32x4  __attribute__((ext_vector_type(4)));
typedef float    v2f    __attribute__((ext_vector_type(2)));
typedef uint32_t u32x4  __attribute__((ext_vector_type(4)));

// v(y) = exp2(q(y)), q = D*y^2 + c1*y + c0 (-0.5*log2e folded in; q <= 0).
// Second-order multiplicative recurrence along the row (step Delta = 16 px):
//   v_{r+1} = v_r * rho_r,  rho_{r+1} = rho_r * sigma
//   rho_0 = exp2(Delta*(D*(2y0+Delta)+c1)),  sigma = exp2(2*D*Delta^2)
// Chains in fp32 (R13's fp16 chains drifted: absmax 3.0); fp16 only at the
// per-step cvt_pkrtz (R12 numerics, absmax 0.5).
//
// R15 = R12 + __launch_bounds__(256,6): LDS 27,136 B x 6 = 162,816 <=
// 163,840 -> 6 blocks/CU resident (24 waves/CU, 6/SIMD) vs R12's 3.
// R12 counters: VALUBusy 71% at 3 waves/SIMD; R7 measured 92% at 4.5+.
// VGPR cap at 6 waves/EU = 85 >= measured 64, no spill.
// (R11 pipelining and R14 forced v_pk_mul_f32 both failed to cut the
// ~600cy/wave-kt codegen glue -> instruction count is at its floor; this
// attacks the 29% stall fraction instead.)
//
// Geometry: block = 256 thr = 4 waves over one 256-px col-group; wave =
// 256-gaussian quarter (8 k-tiles) x 16 m-tiles (256 px); partials tree-
// reduced through LDS (aliased over the dead coeff table). 2304 blocks.
//
// MFMA 16x16x32 f16: A[m=lane&15][k=quad*8+j]; C/D col=lane&15 (ch),
// row=quad*4+reg (px). Coeff LDS: float4 {D,c1,c0,sigma} per gaussian,
// [kt][quad][slot0..8] 9-slot pad -> quad bank starts {0,4,8,12}:
// conflict-free b128. W rows {r,g,b,0} stride 1040 fp16 (2-way = free).
__global__ __launch_bounds__(256, 6) void render_kernel(
    const float2* __restrict__ means2,   // (N,2,1) -> {mx,my}
    const float4* __restrict__ covs4,    // (N,2,2) -> {a,b,c,d}
    const float4* __restrict__ colors4,  // (N,4)   -> {cr,cg,cb,alpha}
    float* __restrict__ out) {
  __shared__ __align__(16) float4 ccf4[32 * 4 * 9];     // 18,432 B (+ red buf)
  __shared__ __align__(16) _Float16 wl[4 * WL_STRIDE];  // 8,320 B

  const int t   = threadIdx.x;          // 0..255
  const int h   = blockIdx.x / 3;       // image row
  const int seg = blockIdx.x % 3;       // 256-px col-group
  const float scale = 1.0f / 767.0f;
  const float x = (float)h * scale;
  const float L = -0.72134752044448170368f;  // -0.5 * log2(e)
  const float Delta = 16.0f * scale;

  // ---- Block prep: 4 gaussians per thread ----
#pragma unroll
  for (int i = 0; i < 4; ++i) {
    const int g = i * 256 + t;
    const float2 mn = means2[g];
    const float4 cv = covs4[g];    // a,b,c,d
    const float4 co = colors4[g];  // cr,cg,cb,alpha
    const float inv = 1.0f / (cv.x * cv.w - cv.y * cv.z);
    const float A  = L * cv.w * inv;
    const float Bc = -L * (cv.y + cv.z) * inv;
    const float D  = L * cv.x * inv;
    const float dx = x - mn.x;
    const float qa = A * dx * dx;
    const float qb = Bc * dx;
    const float c1 = fmaf(-2.0f * D, mn.y, qb);
    const float c0 = fmaf(fmaf(D, mn.y, -qb), mn.y, qa);
    const float sg = __builtin_amdgcn_exp2f(2.0f * D * Delta * Delta);
    ccf4[(g >> 5) * 36 + ((g >> 3) & 3) * 9 + (g & 7)] =
        make_float4(D, c1, c0, sg);
    const float al = co.w;
    wl[0 * WL_STRIDE + g] = (_Float16)(al / (1.0f + expf(-co.x)));
    wl[1 * WL_STRIDE + g] = (_Float16)(al / (1.0f + expf(-co.y)));
    wl[2 * WL_STRIDE + g] = (_Float16)(al / (1.0f + expf(-co.z)));
    wl[3 * WL_STRIDE + g] = (_Float16)0.0f;
  }
  __syncthreads();

  // ---- Per-wave setup: wave = gaussian quarter, 16 m-tiles (256 px) ----
  const int lane = t & 63;
  const int wq   = t >> 6;              // gaussian quarter 0..3
  const int m    = lane & 15;
  const int quad = lane >> 4;
  const int px0  = seg * 256;
  const float y0 = (float)(px0 + m) * scale;
  const float u  = fmaf(2.0f, y0, Delta);   // rho_0 exponent helper
  const int n4 = (m < 3) ? m : 3;

  // wave wq handles global k-tiles wq*8 .. wq*8+7
  const float4* cbase = ccf4 + (wq * 8) * 36 + quad * 9;   // + ktl*36
  const _Float16* wbase = &wl[n4 * WL_STRIDE + (wq * 8) * 32 + quad * 8];

  f32x4 acc[16];
#pragma unroll
  for (int r = 0; r < 16; ++r) acc[r] = (f32x4){0.f, 0.f, 0.f, 0.f};

  for (int ktl = 0; ktl < 8; ++ktl) {
    const float4* cp = cbase + ktl * 36;
    float4 c[8];
#pragma unroll
    for (int j = 0; j < 8; ++j) c[j] = cp[j];   // 8x ds_read_b128, bank-clean

    const half8 b = *(const half8*)(wbase + ktl * 32);

    // anchors + ratios (2 exps per gaussian, bounded fp32)
    v2f vv[4], rr[4], ss[4];
#pragma unroll
    for (int j = 0; j < 8; ++j) {
      const float q0  = fmaf(fmaf(c[j].x, y0, c[j].y), y0, c[j].z);
      const float rex = Delta * fmaf(c[j].x, u, c[j].y);
      vv[j >> 1][j & 1] = __builtin_amdgcn_exp2f(q0);
      rr[j >> 1][j & 1] = __builtin_amdgcn_exp2f(rex);
      ss[j >> 1][j & 1] = c[j].w;
    }

#pragma unroll
    for (int r = 0; r < 16; ++r) {
      u32x4 pa;
#pragma unroll
      for (int p = 0; p < 4; ++p) {
        const fp16x2 hp = __builtin_amdgcn_cvt_pkrtz(vv[p].x, vv[p].y);
        pa[p] = __builtin_bit_cast(uint32_t, hp);
      }
      acc[r] = __builtin_amdgcn_mfma_f32_16x16x32_f16(
          __builtin_bit_cast(half8, pa), b, acc[r], 0, 0, 0);
      if (r < 15) {
#pragma unroll
        for (int p = 0; p < 4; ++p) {   // v_pk_mul_f32 chains
          vv[p] *= rr[p];
          rr[p] *= ss[p];
        }
      }
    }
  }

  // ---- Epilogue: tree-reduce the 4 gaussian-quarter partials via LDS ----
  __syncthreads();                       // all waves done reading ccf4/wl
  float* red = (float*)ccf4;             // 3 x 768 floats, aliased
  if (wq > 0 && m < 3) {
    float* buf = red + (wq - 1) * 768;
#pragma unroll
    for (int r = 0; r < 16; ++r) {
#pragma unroll
      for (int reg = 0; reg < 4; ++reg) {
        const int pxl = 16 * r + quad * 4 + reg;   // 0..255
        buf[pxl * 3 + m] = acc[r][reg];
      }
    }
  }
  __syncthreads();
  if (wq == 0 && m < 3) {
#pragma unroll
    for (int r = 0; r < 16; ++r) {
#pragma unroll
      for (int reg = 0; reg < 4; ++reg) {
        const int pxl = 16 * r + quad * 4 + reg;
        const float s = acc[r][reg] + red[pxl * 3 + m] +
                        red[768 + pxl * 3 + m] + red[1536 + pxl * 3 + m];
        out[((size_t)h * W_DIM + px0 + pxl) * 3 + m] = s;
      }
    }
  }
}

extern "C" void kernel_launch(void* const* d_in, const int* in_sizes, int n_in,
                              void* d_out, int out_size, void* d_ws, size_t ws_size,
                              hipStream_t stream) {
  const float2* means2  = (const float2*)d_in[0];   // (N,2,1)
  const float4* covs4   = (const float4*)d_in[1];   // (N,2,2)
  const float4* colors4 = (const float4*)d_in[2];   // (N,4)
  float* out = (float*)d_out;                       // (768,768,3) fp32

  // 2304 blocks = 768 rows x 3 col-groups; 256 thr = 4 gaussian-quarter waves.
  render_kernel<<<dim3(H_DIM * 3), dim3(256), 0, stream>>>(
      means2, covs4, colors4, out);
}

// Round 17
// 107.717 us; speedup vs baseline: 2.3634x; 2.3634x over previous
//
#include <hip/hip_runtime.h>
#include <stdint.h>

#define N_GAUSS 1024
#define H_DIM 768
#define W_DIM 768
#define WL_STRIDE 1040  // fp16 W row stride: row bank offset 8 -> 2-way (free)

typedef _Float16 half8  __attribute__((ext_vector_type(8)));
typedef __fp16   fp16x2 __attribute__((ext_vector_type(2)));
typedef float    f32x4  __attribute__((ext_vector_type(4)));
typedef float    v2f    __attribute__((ext_vector_type(2)));
typedef uint32_t u32x4  __attribute__((ext_vector_type(4)));

// v(y) = exp2(q(y)), q = D*y^2 + c1*y + c0 (-0.5*log2e folded in; q <= 0).
// Second-order multiplicative recurrence along the row (step Delta = 16 px):
//   v_{r+1} = v_r * rho_r,  rho_{r+1} = rho_r * sigma
//   rho_0 = exp2(Delta*(D*(2y0+Delta)+c1)),  sigma = exp2(2*D*Delta^2)
// Chains in fp32 (R13's fp16 chains drift ~r^2/2*2^-11: absmax 3.0 FAIL);
// fp16 only at the per-step cvt_pkrtz (absmax 0.5 PASS).
//
// R16 = R12 verbatim (best of session: 107.8 us total, render 61 us).
// Probed and rejected variants:
//   R11 SW-pipelined LDS prefetch: +11 us (compiler already optimal)
//   R13 fp16 chains: absmax fail
//   R14 inline-asm v_pk_mul_f32: neutral (already packed)
//   R15 launch_bounds(256,6): acc[16] (64 AGPR) + 64 VGPR = 128 regs/wave;
//       capping at 6 waves/EU spills acc to scratch -> 700 GB writes, 200 us.
//       Unified RF: 128 regs -> 4 waves/EU is the occupancy cap. Do NOT
//       raise the min-waves bound.
//
// Geometry: block = 256 thr = 4 waves over one 256-px col-group; wave =
// 256-gaussian quarter (8 k-tiles) x 16 m-tiles (256 px); partials tree-
// reduced through LDS (aliased over the dead coeff table). 2304 blocks.
//
// MFMA 16x16x32 f16: A[m=lane&15][k=quad*8+j]; C/D col=lane&15 (ch),
// row=quad*4+reg (px). Coeff LDS: float4 {D,c1,c0,sigma} per gaussian,
// [kt][quad][slot0..8] 9-slot pad -> quad bank starts {0,4,8,12}:
// conflict-free b128. W rows {r,g,b,0} stride 1040 fp16 (2-way = free).
__global__ __launch_bounds__(256, 3) void render_kernel(
    const float2* __restrict__ means2,   // (N,2,1) -> {mx,my}
    const float4* __restrict__ covs4,    // (N,2,2) -> {a,b,c,d}
    const float4* __restrict__ colors4,  // (N,4)   -> {cr,cg,cb,alpha}
    float* __restrict__ out) {
  __shared__ __align__(16) float4 ccf4[32 * 4 * 9];     // 18,432 B (+ red buf)
  __shared__ __align__(16) _Float16 wl[4 * WL_STRIDE];  // 8,320 B

  const int t   = threadIdx.x;          // 0..255
  const int h   = blockIdx.x / 3;       // image row
  const int seg = blockIdx.x % 3;       // 256-px col-group
  const float scale = 1.0f / 767.0f;
  const float x = (float)h * scale;
  const float L = -0.72134752044448170368f;  // -0.5 * log2(e)
  const float Delta = 16.0f * scale;

  // ---- Block prep: 4 gaussians per thread ----
#pragma unroll
  for (int i = 0; i < 4; ++i) {
    const int g = i * 256 + t;
    const float2 mn = means2[g];
    const float4 cv = covs4[g];    // a,b,c,d
    const float4 co = colors4[g];  // cr,cg,cb,alpha
    const float inv = 1.0f / (cv.x * cv.w - cv.y * cv.z);
    const float A  = L * cv.w * inv;
    const float Bc = -L * (cv.y + cv.z) * inv;
    const float D  = L * cv.x * inv;
    const float dx = x - mn.x;
    const float qa = A * dx * dx;
    const float qb = Bc * dx;
    const float c1 = fmaf(-2.0f * D, mn.y, qb);
    const float c0 = fmaf(fmaf(D, mn.y, -qb), mn.y, qa);
    const float sg = __builtin_amdgcn_exp2f(2.0f * D * Delta * Delta);
    ccf4[(g >> 5) * 36 + ((g >> 3) & 3) * 9 + (g & 7)] =
        make_float4(D, c1, c0, sg);
    const float al = co.w;
    wl[0 * WL_STRIDE + g] = (_Float16)(al / (1.0f + expf(-co.x)));
    wl[1 * WL_STRIDE + g] = (_Float16)(al / (1.0f + expf(-co.y)));
    wl[2 * WL_STRIDE + g] = (_Float16)(al / (1.0f + expf(-co.z)));
    wl[3 * WL_STRIDE + g] = (_Float16)0.0f;
  }
  __syncthreads();

  // ---- Per-wave setup: wave = gaussian quarter, 16 m-tiles (256 px) ----
  const int lane = t & 63;
  const int wq   = t >> 6;              // gaussian quarter 0..3
  const int m    = lane & 15;
  const int quad = lane >> 4;
  const int px0  = seg * 256;
  const float y0 = (float)(px0 + m) * scale;
  const float u  = fmaf(2.0f, y0, Delta);   // rho_0 exponent helper
  const int n4 = (m < 3) ? m : 3;

  // wave wq handles global k-tiles wq*8 .. wq*8+7
  const float4* cbase = ccf4 + (wq * 8) * 36 + quad * 9;   // + ktl*36
  const _Float16* wbase = &wl[n4 * WL_STRIDE + (wq * 8) * 32 + quad * 8];

  f32x4 acc[16];
#pragma unroll
  for (int r = 0; r < 16; ++r) acc[r] = (f32x4){0.f, 0.f, 0.f, 0.f};

  for (int ktl = 0; ktl < 8; ++ktl) {
    const float4* cp = cbase + ktl * 36;
    float4 c[8];
#pragma unroll
    for (int j = 0; j < 8; ++j) c[j] = cp[j];   // 8x ds_read_b128, bank-clean

    const half8 b = *(const half8*)(wbase + ktl * 32);

    // anchors + ratios (2 exps per gaussian, bounded fp32)
    v2f vv[4], rr[4], ss[4];
#pragma unroll
    for (int j = 0; j < 8; ++j) {
      const float q0  = fmaf(fmaf(c[j].x, y0, c[j].y), y0, c[j].z);
      const float rex = Delta * fmaf(c[j].x, u, c[j].y);
      vv[j >> 1][j & 1] = __builtin_amdgcn_exp2f(q0);
      rr[j >> 1][j & 1] = __builtin_amdgcn_exp2f(rex);
      ss[j >> 1][j & 1] = c[j].w;
    }

#pragma unroll
    for (int r = 0; r < 16; ++r) {
      u32x4 pa;
#pragma unroll
      for (int p = 0; p < 4; ++p) {
        const fp16x2 hp = __builtin_amdgcn_cvt_pkrtz(vv[p].x, vv[p].y);
        pa[p] = __builtin_bit_cast(uint32_t, hp);
      }
      acc[r] = __builtin_amdgcn_mfma_f32_16x16x32_f16(
          __builtin_bit_cast(half8, pa), b, acc[r], 0, 0, 0);
      if (r < 15) {
#pragma unroll
        for (int p = 0; p < 4; ++p) {   // v_pk_mul_f32 chains
          vv[p] *= rr[p];
          rr[p] *= ss[p];
        }
      }
    }
  }

  // ---- Epilogue: tree-reduce the 4 gaussian-quarter partials via LDS ----
  __syncthreads();                       // all waves done reading ccf4/wl
  float* red = (float*)ccf4;             // 3 x 768 floats, aliased
  if (wq > 0 && m < 3) {
    float* buf = red + (wq - 1) * 768;
#pragma unroll
    for (int r = 0; r < 16; ++r) {
#pragma unroll
      for (int reg = 0; reg < 4; ++reg) {
        const int pxl = 16 * r + quad * 4 + reg;   // 0..255
        buf[pxl * 3 + m] = acc[r][reg];
      }
    }
  }
  __syncthreads();
  if (wq == 0 && m < 3) {
#pragma unroll
    for (int r = 0; r < 16; ++r) {
#pragma unroll
      for (int reg = 0; reg < 4; ++reg) {
        const int pxl = 16 * r + quad * 4 + reg;
        const float s = acc[r][reg] + red[pxl * 3 + m] +
                        red[768 + pxl * 3 + m] + red[1536 + pxl * 3 + m];
        out[((size_t)h * W_DIM + px0 + pxl) * 3 + m] = s;
      }
    }
  }
}

extern "C" void kernel_launch(void* const* d_in, const int* in_sizes, int n_in,
                              void* d_out, int out_size, void* d_ws, size_t ws_size,
                              hipStream_t stream) {
  const float2* means2  = (const float2*)d_in[0];   // (N,2,1)
  const float4* covs4   = (const float4*)d_in[1];   // (N,2,2)
  const float4* colors4 = (const float4*)d_in[2];   // (N,4)
  float* out = (float*)d_out;                       // (768,768,3) fp32

  // 2304 blocks = 768 rows x 3 col-groups; 256 thr = 4 gaussian-quarter waves.
  render_kernel<<<dim3(H_DIM * 3), dim3(256), 0, stream>>>(
      means2, covs4, colors4, out);
}